// Round 6
// baseline (399.510 us; speedup 1.0000x reference)
//
#include <hip/hip_runtime.h>

// Single-head attention, B=4, S=2048, D=1024. fp32 in, fp32 out.
// FAST PATH (ws >= 121 MiB): all-MFMA pipeline, bf16 compute, fp32 accum.
// GEMM engine: m97-style 128x128 tile, BK=32, global_load_lds(16B) staging,
// unpadded 16KB LDS, 2-barrier K-loop. QKV fused into one z=3 dispatch.
// P = exp(mask(Q@K^T/32)) with no max-subtraction (logits bounded; exact for
// masked -> 0). FALLBACK (small ws): round-4 proven VALU pipeline (48 MB).

#define DM 1024
#define SQ 2048
#define NB 4
typedef unsigned short U16;
typedef short bhalf8 __attribute__((ext_vector_type(8)));
typedef float f32x4 __attribute__((ext_vector_type(4)));

__device__ inline U16 f2bf(float f) {
  unsigned int u = __float_as_uint(f);
  u += 0x7FFFu + ((u >> 16) & 1u);  // RNE
  return (U16)(u >> 16);
}
__device__ inline float2 bfp2(unsigned int u) {
  float2 r;
  r.x = __uint_as_float(u << 16);
  r.y = __uint_as_float(u & 0xffff0000u);
  return r;
}
__device__ inline unsigned int packbf(float a, float b) {
  return (unsigned int)f2bf(a) | ((unsigned int)f2bf(b) << 16);
}

// async global->LDS, 16B per lane; LDS dest = wave-uniform base + lane*16
__device__ inline void gload16(const U16* g, U16* l) {
  __builtin_amdgcn_global_load_lds(
      (const __attribute__((address_space(1))) unsigned int*)g,
      (__attribute__((address_space(3))) unsigned int*)l, 16, 0, 0);
}

// ---------------------------------------------------------------- fast path --
__global__ __launch_bounds__(256) void conv_f32_bf16(
    const float* __restrict__ src, U16* __restrict__ dst) {
  int i = (blockIdx.x * 256 + threadIdx.x) * 8;
  float4 a = *(const float4*)(src + i);
  float4 b = *(const float4*)(src + i + 4);
  uint4 w;
  w.x = packbf(a.x, a.y); w.y = packbf(a.z, a.w);
  w.z = packbf(b.x, b.y); w.w = packbf(b.z, b.w);
  *(uint4*)(dst + i) = w;
}

// transpose [R][C] (TIN) -> bf16 [C][R]; R,C multiples of 64; grid(C/64,R/64,Z)
__device__ inline void ldcvt16(const float* p, U16* d) {
#pragma unroll
  for (int i = 0; i < 4; ++i) {
    float4 f = *(const float4*)(p + i * 4);
    d[i * 4 + 0] = f2bf(f.x); d[i * 4 + 1] = f2bf(f.y);
    d[i * 4 + 2] = f2bf(f.z); d[i * 4 + 3] = f2bf(f.w);
  }
}
__device__ inline void ldcvt16(const U16* p, U16* d) {
  uint4 a = *(const uint4*)p;
  uint4 b = *(const uint4*)(p + 8);
  *(uint4*)d = a;
  *(uint4*)(d + 8) = b;
}
template <typename TIN>
__global__ __launch_bounds__(256) void transp_to_bf16(
    const TIN* __restrict__ src, U16* __restrict__ dst, int R, int C) {
  __shared__ U16 tile[64][72];
  const int z = blockIdx.z;
  src += (size_t)z * R * C;
  dst += (size_t)z * R * C;
  const int r0 = blockIdx.y * 64, c0 = blockIdx.x * 64;
  const int t = threadIdx.x;
  const int tr = t >> 2, tc = (t & 3) * 16;
  ldcvt16(src + (size_t)(r0 + tr) * C + c0 + tc, &tile[tr][tc]);
  __syncthreads();
  U16 vals[16];
#pragma unroll
  for (int m = 0; m < 16; ++m) vals[m] = tile[tc + m][tr];
  U16* op = dst + (size_t)(c0 + tr) * R + r0 + tc;
  *(uint4*)op = *(uint4*)&vals[0];
  *(uint4*)(op + 8) = *(uint4*)&vals[8];
}

// C = A @ B'^T : A[M][K] bf16, B'[N][K] bf16, fp32 accum. 128x128 tile, 4 waves,
// BK=32, global_load_lds staging into unpadded LDS [128][32] (8KB each).
// EP: 0 = bf16 store, 1 = exp(mask(acc*scale)) bf16, 2 = acc/rowsum bf16,
// 3 = fp32 store. Verified layouts: A/B frag [lane&15][k=(lane>>4)*8+j],
// C/D row=(lane>>4)*4+reg, col=lane&15.
template <int EP>
__global__ __launch_bounds__(256) void gemm_mfma(
    const U16* __restrict__ A, const U16* __restrict__ B, void* __restrict__ Cv,
    int M, int N, int K, long long sA, long long sB, long long sC,
    const int* __restrict__ mask, const float* __restrict__ rowsum, float scale) {
  __shared__ U16 As[128 * 32];  // [m][k] row-major, 64B rows
  __shared__ U16 Bs[128 * 32];  // [n][k]
  const int t = threadIdx.x;
  const int lane = t & 63, wave = t >> 6;
  const int wm = wave >> 1, wn = wave & 1;
  const int q = lane >> 4, ln = lane & 15;
  const int z = blockIdx.z;
  const int m0 = blockIdx.y * 128, n0 = blockIdx.x * 128;
  A += (size_t)z * sA;
  B += (size_t)z * sB;

  f32x4 acc[4][4] = {};

  // staging: wave w covers rows [w*32, w*32+32) of each tile; 2 calls per tile.
  // call c: lane L -> row w*32 + c*16 + (L>>2), col elems (L&3)*8.
  const int rsub = lane >> 2;
  const int csub = (lane & 3) * 8;
  const U16* ga0 = A + (size_t)(m0 + wave * 32 + rsub) * K + csub;
  const U16* ga1 = ga0 + (size_t)16 * K;
  const U16* gb0 = B + (size_t)(n0 + wave * 32 + rsub) * K + csub;
  const U16* gb1 = gb0 + (size_t)16 * K;
  U16* la0 = As + wave * 1024;        // bytes: wave*2048
  U16* la1 = la0 + 512;
  U16* lb0 = Bs + wave * 1024;
  U16* lb1 = lb0 + 512;

  for (int k0 = 0; k0 < K; k0 += 32) {
    gload16(ga0, la0);
    gload16(ga1, la1);
    gload16(gb0, lb0);
    gload16(gb1, lb1);
    ga0 += 32; ga1 += 32; gb0 += 32; gb1 += 32;
    __syncthreads();  // drains vmcnt (global_load_lds) + orders LDS
    bhalf8 af[4], bg[4];
#pragma unroll
    for (int i = 0; i < 4; ++i) {
      af[i] = *(const bhalf8*)&As[(wm * 64 + i * 16 + ln) * 32 + q * 8];
      bg[i] = *(const bhalf8*)&Bs[(wn * 64 + i * 16 + ln) * 32 + q * 8];
    }
#pragma unroll
    for (int i = 0; i < 4; ++i)
#pragma unroll
      for (int j = 0; j < 4; ++j)
        acc[i][j] = __builtin_amdgcn_mfma_f32_16x16x32_bf16(af[i], bg[j], acc[i][j], 0, 0, 0);
    __syncthreads();
  }

  // epilogue
#pragma unroll
  for (int i = 0; i < 4; ++i) {
#pragma unroll
    for (int r = 0; r < 4; ++r) {
      const int rr = m0 + wm * 64 + i * 16 + q * 4 + r;
      float linv = 0.f;
      if constexpr (EP == 2) linv = 1.0f / rowsum[(size_t)z * M + rr];
#pragma unroll
      for (int j = 0; j < 4; ++j) {
        const int c = n0 + wn * 64 + j * 16 + ln;
        float v = acc[i][j][r];
        if constexpr (EP == 0) {
          ((U16*)Cv)[(size_t)z * sC + (size_t)rr * N + c] = f2bf(v);
        } else if constexpr (EP == 1) {
          int mk = mask[((size_t)z * M + rr) * N + c];
          float p = mk ? __expf(v * scale) : 0.f;
          ((U16*)Cv)[(size_t)z * sC + (size_t)rr * N + c] = f2bf(p);
        } else if constexpr (EP == 2) {
          ((U16*)Cv)[(size_t)z * sC + (size_t)rr * N + c] = f2bf(v * linv);
        } else {
          ((float*)Cv)[(size_t)z * sC + (size_t)rr * N + c] = v;
        }
      }
    }
  }
}

// rowsum over P rows: 4 waves/block, 1 wave = 1 row of 2048 bf16
__global__ __launch_bounds__(256) void rowsum_k(
    const U16* __restrict__ P, float* __restrict__ rs) {
  const int t = threadIdx.x;
  const int w = t >> 6, lane = t & 63;
  const int row = blockIdx.x * 4 + w;
  const U16* p = P + (size_t)row * SQ;
  float s = 0.f;
#pragma unroll
  for (int it = 0; it < 4; ++it) {
    uint4 v = *(const uint4*)(p + it * 512 + lane * 8);
    float2 a = bfp2(v.x), b = bfp2(v.y), c = bfp2(v.z), d = bfp2(v.w);
    s += a.x + a.y + b.x + b.y + c.x + c.y + d.x + d.y;
  }
#pragma unroll
  for (int off = 32; off > 0; off >>= 1) s += __shfl_xor(s, off, 64);
  if (lane == 0) rs[row] = s + 1e-30f;
}

// ------------------------------------------------------------ fallback path --
__device__ inline float4 load4(const float* p) { return *(const float4*)p; }
__device__ inline float4 load4(const U16* p) {
  uint2 w = *(const uint2*)p;
  float2 f0 = bfp2(w.x), f1 = bfp2(w.y);
  return make_float4(f0.x, f0.y, f1.x, f1.y);
}
__device__ inline void store4(float* p, float a, float b, float c, float d) {
  *(float4*)p = make_float4(a, b, c, d);
}
__device__ inline void store4(U16* p, float a, float b, float c, float d) {
  uint2 w;
  w.x = packbf(a, b);
  w.y = packbf(c, d);
  *(uint2*)p = w;
}
template <typename TA, typename TB, typename TC>
__global__ __launch_bounds__(256) void gemm_t(
    const TA* __restrict__ A, const TB* __restrict__ B,
    TC* __restrict__ C, int M, int N, int K) {
  __shared__ float As[16][64];
  __shared__ float Bs[16][64];
  const int t = threadIdx.x;
  const int tx = t & 15, ty = t >> 4;
  const int m0 = blockIdx.y * 64;
  const int n0 = blockIdx.x * 64;
  const int arow = t >> 2, akq = (t & 3) * 4;
  const int brow = t >> 4, bcg = (t & 15) * 4;
  float acc[4][4] = {};
  for (int k0 = 0; k0 < K; k0 += 16) {
    {
      float4 f = load4(A + (size_t)(m0 + arow) * K + k0 + akq);
      As[akq + 0][arow] = f.x; As[akq + 1][arow] = f.y;
      As[akq + 2][arow] = f.z; As[akq + 3][arow] = f.w;
    }
    {
      float4 f = load4(B + (size_t)(k0 + brow) * N + n0 + bcg);
      *(float4*)&Bs[brow][bcg] = f;
    }
    __syncthreads();
#pragma unroll
    for (int kk = 0; kk < 16; ++kk) {
      float4 a = *(const float4*)&As[kk][ty * 4];
      float4 b = *(const float4*)&Bs[kk][tx * 4];
      float av[4] = {a.x, a.y, a.z, a.w};
      float bv[4] = {b.x, b.y, b.z, b.w};
#pragma unroll
      for (int i = 0; i < 4; ++i)
#pragma unroll
        for (int j = 0; j < 4; ++j) acc[i][j] += av[i] * bv[j];
    }
    __syncthreads();
  }
#pragma unroll
  for (int i = 0; i < 4; ++i)
    store4(&C[(size_t)(m0 + ty * 4 + i) * N + n0 + tx * 4],
           acc[i][0], acc[i][1], acc[i][2], acc[i][3]);
}
__global__ __launch_bounds__(256) void flash_wave(
    const U16* __restrict__ Q, const U16* __restrict__ Kd,
    const U16* __restrict__ V, const int* __restrict__ mask,
    U16* __restrict__ O) {
  __shared__ float q_s[4][DM];
  const int t = threadIdx.x;
  const int w = t >> 6;
  const int lane = t & 63;
  const int row = blockIdx.x * 4 + w;
  const int b = row >> 11;
  const size_t bo = (size_t)b * SQ * DM;
  const size_t mrow0 = (size_t)row * SQ;
  {
    const U16* qp = Q + (size_t)row * DM + lane * 16;
    uint4 w0 = *(const uint4*)qp;
    uint4 w1 = *(const uint4*)(qp + 8);
    float* dst = &q_s[w][lane * 16];
    float2 f;
    f = bfp2(w0.x); dst[0] = f.x;  dst[1] = f.y;
    f = bfp2(w0.y); dst[2] = f.x;  dst[3] = f.y;
    f = bfp2(w0.z); dst[4] = f.x;  dst[5] = f.y;
    f = bfp2(w0.w); dst[6] = f.x;  dst[7] = f.y;
    f = bfp2(w1.x); dst[8] = f.x;  dst[9] = f.y;
    f = bfp2(w1.y); dst[10] = f.x; dst[11] = f.y;
    f = bfp2(w1.z); dst[12] = f.x; dst[13] = f.y;
    f = bfp2(w1.w); dst[14] = f.x; dst[15] = f.y;
  }
  __syncthreads();
  float m = -3.0e38f, l = 0.f;
  float o[16] = {};
  const int dbase = lane * 16;
  const float* qrow = q_s[w];
  for (int j0 = 0; j0 < SQ; j0 += 64) {
    float s;
    {
      const U16* kp = Kd + bo + (size_t)(j0 + lane) * DM;
      float acc = 0.f;
      for (int d = 0; d < DM; d += 8) {
        uint4 kw = *(const uint4*)(kp + d);
        float2 a0 = bfp2(kw.x), a1 = bfp2(kw.y), a2 = bfp2(kw.z), a3 = bfp2(kw.w);
        acc += qrow[d] * a0.x + qrow[d + 1] * a0.y + qrow[d + 2] * a1.x +
               qrow[d + 3] * a1.y + qrow[d + 4] * a2.x + qrow[d + 5] * a2.y +
               qrow[d + 6] * a3.x + qrow[d + 7] * a3.y;
      }
      s = acc * 0.03125f;
      if (mask[mrow0 + j0 + lane] == 0) s = -1e10f;
    }
    float ms = s;
#pragma unroll
    for (int off = 32; off > 0; off >>= 1) ms = fmaxf(ms, __shfl_xor(ms, off, 64));
    float mn = fmaxf(m, ms);
    float alpha = __expf(m - mn);
    float p = __expf(s - mn);
    float ps = p;
#pragma unroll
    for (int off = 32; off > 0; off >>= 1) ps += __shfl_xor(ps, off, 64);
    l = l * alpha + ps;
    m = mn;
#pragma unroll
    for (int k = 0; k < 16; ++k) o[k] *= alpha;
    const U16* vp = V + bo + (size_t)j0 * DM + dbase;
    for (int j = 0; j < 64; ++j) {
      float pj = __shfl(p, j, 64);
      uint4 v0 = *(const uint4*)(vp + (size_t)j * DM);
      uint4 v1 = *(const uint4*)(vp + (size_t)j * DM + 8);
      float2 f0 = bfp2(v0.x), f1 = bfp2(v0.y), f2 = bfp2(v0.z), f3 = bfp2(v0.w);
      float2 g0 = bfp2(v1.x), g1 = bfp2(v1.y), g2 = bfp2(v1.z), g3 = bfp2(v1.w);
      o[0] += pj * f0.x;  o[1] += pj * f0.y;  o[2] += pj * f1.x;  o[3] += pj * f1.y;
      o[4] += pj * f2.x;  o[5] += pj * f2.y;  o[6] += pj * f3.x;  o[7] += pj * f3.y;
      o[8] += pj * g0.x;  o[9] += pj * g0.y;  o[10] += pj * g1.x; o[11] += pj * g1.y;
      o[12] += pj * g2.x; o[13] += pj * g2.y; o[14] += pj * g3.x; o[15] += pj * g3.y;
    }
  }
  float linv = (l > 0.f) ? (1.0f / l) : 0.f;
  U16* op = O + (size_t)row * DM + dbase;
  uint4 r0, r1;
  r0.x = packbf(o[0] * linv, o[1] * linv);
  r0.y = packbf(o[2] * linv, o[3] * linv);
  r0.z = packbf(o[4] * linv, o[5] * linv);
  r0.w = packbf(o[6] * linv, o[7] * linv);
  r1.x = packbf(o[8] * linv, o[9] * linv);
  r1.y = packbf(o[10] * linv, o[11] * linv);
  r1.z = packbf(o[12] * linv, o[13] * linv);
  r1.w = packbf(o[14] * linv, o[15] * linv);
  *(uint4*)op = r0;
  *(uint4*)(op + 8) = r1;
}

extern "C" void kernel_launch(void* const* d_in, const int* in_sizes, int n_in,
                              void* d_out, int out_size, void* d_ws, size_t ws_size,
                              hipStream_t stream) {
  const float* x  = (const float*)d_in[0];
  const int* mask = (const int*)d_in[1];
  const float* Wq = (const float*)d_in[2];
  const float* Wk = (const float*)d_in[3];
  const float* Wv = (const float*)d_in[4];
  const float* Wo = (const float*)d_in[5];
  float* out = (float*)d_out;

  const size_t MB = 1u << 20;
  const size_t E = (size_t)NB * SQ * DM;  // 8388608
  const size_t WE = (size_t)DM * DM;      // 1048576

  if (ws_size >= 121 * MB) {
    // -------- fast MFMA path --------
    char* ws = (char*)d_ws;
    U16* WT   = (U16*)ws;               // 4 x 2MiB: Wq^T,Wk^T,Wv^T,Wo^T bf16
    U16* x16  = (U16*)(ws + 8 * MB);
    U16* Q16  = (U16*)(ws + 24 * MB);   // Q,K,V contiguous at stride E elems
    U16* K16  = (U16*)(ws + 40 * MB);
    U16* V16  = (U16*)(ws + 56 * MB);
    U16* VT16 = (U16*)(ws + 72 * MB);
    U16* P16  = (U16*)(ws + 88 * MB);   // 32 MiB
    float* rs = (float*)(ws + 120 * MB);
    U16* O16  = Q16;                    // Q dead after score GEMM

    conv_f32_bf16<<<dim3(E / (256 * 8)), 256, 0, stream>>>(x, x16);
    dim3 tw(16, 16, 1);
    transp_to_bf16<float><<<tw, 256, 0, stream>>>(Wq, WT + 0 * WE, DM, DM);
    transp_to_bf16<float><<<tw, 256, 0, stream>>>(Wk, WT + 1 * WE, DM, DM);
    transp_to_bf16<float><<<tw, 256, 0, stream>>>(Wv, WT + 2 * WE, DM, DM);
    transp_to_bf16<float><<<tw, 256, 0, stream>>>(Wo, WT + 3 * WE, DM, DM);

    // fused QKV: z in {0,1,2} -> Wq/Wk/Wv, writes Q16/K16/V16
    gemm_mfma<0><<<dim3(DM / 128, (NB * SQ) / 128, 3), 256, 0, stream>>>(
        x16, WT, Q16, NB * SQ, DM, DM,
        0, (long long)WE, (long long)E, nullptr, nullptr, 0.f);

    transp_to_bf16<U16><<<dim3(DM / 64, SQ / 64, NB), 256, 0, stream>>>(V16, VT16, SQ, DM);

    gemm_mfma<1><<<dim3(SQ / 128, SQ / 128, NB), 256, 0, stream>>>(
        Q16, K16, P16, SQ, SQ, DM,
        (long long)SQ * DM, (long long)SQ * DM, (long long)SQ * SQ,
        mask, nullptr, 0.03125f);

    rowsum_k<<<dim3((NB * SQ) / 4), 256, 0, stream>>>(P16, rs);

    gemm_mfma<2><<<dim3(DM / 128, SQ / 128, NB), 256, 0, stream>>>(
        P16, VT16, O16, SQ, DM, SQ,
        (long long)SQ * SQ, (long long)DM * SQ, (long long)SQ * DM,
        nullptr, rs, 0.f);

    gemm_mfma<3><<<dim3(DM / 128, (NB * SQ) / 128, 1), 256, 0, stream>>>(
        O16, WT + 3 * WE, out, NB * SQ, DM, DM,
        0, 0, 0, nullptr, nullptr, 0.f);
  } else {
    // -------- round-4 proven fallback (48 MB) --------
    U16* Kw = (U16*)d_ws;
    U16* Vw = Kw + E;
    U16* Qw = Vw + E;
    U16* Ow = Qw;
    dim3 blk(256);
    dim3 gg(DM / 64, (NB * SQ) / 64);
    gemm_t<float, float, U16><<<gg, blk, 0, stream>>>(x, Wk, Kw, NB * SQ, DM, DM);
    gemm_t<float, float, U16><<<gg, blk, 0, stream>>>(x, Wv, Vw, NB * SQ, DM, DM);
    gemm_t<float, float, U16><<<gg, blk, 0, stream>>>(x, Wq, Qw, NB * SQ, DM, DM);
    flash_wave<<<dim3((NB * SQ) / 4), blk, 0, stream>>>(Qw, Kw, Vw, mask, Ow);
    gemm_t<U16, float, float><<<gg, blk, 0, stream>>>(Ow, Wo, out, NB * SQ, DM, DM);
  }
}

// Round 7
// 365.699 us; speedup vs baseline: 1.0925x; 1.0925x over previous
//
#include <hip/hip_runtime.h>

// Single-head attention, B=4, S=2048, D=1024. fp32 in, fp32 out.
// FAST PATH (ws >= 121 MiB): all-MFMA pipeline, bf16 compute, fp32 accum.
// Engine: round-5 proven 128x128 tile, BK=64, padded LDS (stride 72), VGPR
// staging, 32 MFMA per barrier-pair (~430 TF at this shape; m97-style
// global_load_lds BK=32 measured SLOWER here - see round-6 post-mortem).
// P = exp(mask(Q@K^T/32)) with no max-subtraction (logits bounded).
// Rowsum fused into score epilogue via shfl-reduce + atomicAdd.
// 7 dispatches: conv(+rs zero), transpW(z4), QKV(z3), transpV(z4), score(z4),
// PV(z4), out. FALLBACK (small ws): round-4 proven VALU pipeline (48 MB).

#define DM 1024
#define SQ 2048
#define NB 4
typedef unsigned short U16;
typedef short bhalf8 __attribute__((ext_vector_type(8)));
typedef float f32x4 __attribute__((ext_vector_type(4)));

__device__ inline U16 f2bf(float f) {
  unsigned int u = __float_as_uint(f);
  u += 0x7FFFu + ((u >> 16) & 1u);  // RNE
  return (U16)(u >> 16);
}
__device__ inline float2 bfp2(unsigned int u) {
  float2 r;
  r.x = __uint_as_float(u << 16);
  r.y = __uint_as_float(u & 0xffff0000u);
  return r;
}
__device__ inline unsigned int packbf(float a, float b) {
  return (unsigned int)f2bf(a) | ((unsigned int)f2bf(b) << 16);
}

// ---------------------------------------------------------------- fast path --
// x fp32 -> bf16; first 32 blocks also zero the rowsum accumulator.
__global__ __launch_bounds__(256) void conv_f32_bf16(
    const float* __restrict__ src, U16* __restrict__ dst, float* __restrict__ rs) {
  int idx = blockIdx.x * 256 + threadIdx.x;
  if (idx < NB * SQ) rs[idx] = 0.f;
  int i = idx * 8;
  float4 a = *(const float4*)(src + i);
  float4 b = *(const float4*)(src + i + 4);
  uint4 w;
  w.x = packbf(a.x, a.y); w.y = packbf(a.z, a.w);
  w.z = packbf(b.x, b.y); w.w = packbf(b.z, b.w);
  *(uint4*)(dst + i) = w;
}

__device__ inline void ldcvt16(const float* p, U16* d) {
#pragma unroll
  for (int i = 0; i < 4; ++i) {
    float4 f = *(const float4*)(p + i * 4);
    d[i * 4 + 0] = f2bf(f.x); d[i * 4 + 1] = f2bf(f.y);
    d[i * 4 + 2] = f2bf(f.z); d[i * 4 + 3] = f2bf(f.w);
  }
}
__device__ inline void ldcvt16(const U16* p, U16* d) {
  uint4 a = *(const uint4*)p;
  uint4 b = *(const uint4*)(p + 8);
  *(uint4*)d = a;
  *(uint4*)(d + 8) = b;
}

// 4 weight matrices [DM][DM] fp32 -> bf16 transposed, one z=4 dispatch
__global__ __launch_bounds__(256) void transp_w4(
    const float* __restrict__ s0, const float* __restrict__ s1,
    const float* __restrict__ s2, const float* __restrict__ s3,
    U16* __restrict__ dst) {
  __shared__ U16 tile[64][72];
  const int z = blockIdx.z;
  const float* src = (z == 0) ? s0 : (z == 1) ? s1 : (z == 2) ? s2 : s3;
  U16* d = dst + (size_t)z * DM * DM;
  const int r0 = blockIdx.y * 64, c0 = blockIdx.x * 64;
  const int t = threadIdx.x;
  const int tr = t >> 2, tc = (t & 3) * 16;
  ldcvt16(src + (size_t)(r0 + tr) * DM + c0 + tc, &tile[tr][tc]);
  __syncthreads();
  U16 vals[16];
#pragma unroll
  for (int m = 0; m < 16; ++m) vals[m] = tile[tc + m][tr];
  U16* op = d + (size_t)(c0 + tr) * DM + r0 + tc;
  *(uint4*)op = *(uint4*)&vals[0];
  *(uint4*)(op + 8) = *(uint4*)&vals[8];
}

// bf16 transpose [R][C] -> [C][R], grid(C/64, R/64, Z)
__global__ __launch_bounds__(256) void transp_bf16(
    const U16* __restrict__ src, U16* __restrict__ dst, int R, int C) {
  __shared__ U16 tile[64][72];
  const int z = blockIdx.z;
  src += (size_t)z * R * C;
  dst += (size_t)z * R * C;
  const int r0 = blockIdx.y * 64, c0 = blockIdx.x * 64;
  const int t = threadIdx.x;
  const int tr = t >> 2, tc = (t & 3) * 16;
  ldcvt16(src + (size_t)(r0 + tr) * C + c0 + tc, &tile[tr][tc]);
  __syncthreads();
  U16 vals[16];
#pragma unroll
  for (int m = 0; m < 16; ++m) vals[m] = tile[tc + m][tr];
  U16* op = dst + (size_t)(c0 + tr) * R + r0 + tc;
  *(uint4*)op = *(uint4*)&vals[0];
  *(uint4*)(op + 8) = *(uint4*)&vals[8];
}

// C = A @ B'^T : A[M][K] bf16, B'[N][K] bf16, fp32 accum. 128x128 tile, 4 waves,
// BK=64, padded LDS stride 72, VGPR staging. EP: 0 = bf16 store,
// 1 = exp(mask(acc*scale)) bf16 + fused rowsum atomics, 2 = acc/rowsum bf16,
// 3 = fp32 store. Verified layouts: A/B frag [lane&15][k=(lane>>4)*8+j],
// C/D row=(lane>>4)*4+reg, col=lane&15.
template <int EP>
__global__ __launch_bounds__(256) void gemm_mfma(
    const U16* __restrict__ A, const U16* __restrict__ B, void* __restrict__ Cv,
    int M, int N, int K, long long sA, long long sB, long long sC,
    const int* __restrict__ mask, float* __restrict__ rowsum, float scale) {
  __shared__ U16 As[128 * 72];  // [m][k], stride 72 elems = 144 B
  __shared__ U16 Bs[128 * 72];  // [n][k]
  const int t = threadIdx.x;
  const int lane = t & 63, wave = t >> 6;
  const int wm = wave >> 1, wn = wave & 1;
  const int q = lane >> 4, ln = lane & 15;
  const int z = blockIdx.z;
  const int m0 = blockIdx.y * 128, n0 = blockIdx.x * 128;
  A += (size_t)z * sA;
  B += (size_t)z * sB;

  f32x4 acc[4][4] = {};

  const int srow = t >> 3;        // 0..31
  const int scol = (t & 7) * 8;   // 0..56 step 8

  for (int k0 = 0; k0 < K; k0 += 64) {
    const U16* ga = A + (size_t)(m0 + srow) * K + k0 + scol;
    const U16* gb = B + (size_t)(n0 + srow) * K + k0 + scol;
#pragma unroll
    for (int it = 0; it < 4; ++it) {
      uint4 va = *(const uint4*)(ga + (size_t)it * 32 * K);
      uint4 vb = *(const uint4*)(gb + (size_t)it * 32 * K);
      *(uint4*)&As[(it * 32 + srow) * 72 + scol] = va;
      *(uint4*)&Bs[(it * 32 + srow) * 72 + scol] = vb;
    }
    __syncthreads();
#pragma unroll
    for (int kk = 0; kk < 64; kk += 32) {
      bhalf8 af[4], bg[4];
#pragma unroll
      for (int i = 0; i < 4; ++i) {
        af[i] = *(const bhalf8*)&As[(wm * 64 + i * 16 + ln) * 72 + kk + q * 8];
        bg[i] = *(const bhalf8*)&Bs[(wn * 64 + i * 16 + ln) * 72 + kk + q * 8];
      }
#pragma unroll
      for (int i = 0; i < 4; ++i)
#pragma unroll
        for (int j = 0; j < 4; ++j)
          acc[i][j] = __builtin_amdgcn_mfma_f32_16x16x32_bf16(af[i], bg[j], acc[i][j], 0, 0, 0);
    }
    __syncthreads();
  }

  // epilogue
#pragma unroll
  for (int i = 0; i < 4; ++i) {
#pragma unroll
    for (int r = 0; r < 4; ++r) {
      const int rr = m0 + wm * 64 + i * 16 + q * 4 + r;
      float linv = 0.f;
      if constexpr (EP == 2) linv = 1.0f / (rowsum[(size_t)z * M + rr] + 1e-30f);
      float psum = 0.f;
#pragma unroll
      for (int j = 0; j < 4; ++j) {
        const int c = n0 + wn * 64 + j * 16 + ln;
        float v = acc[i][j][r];
        if constexpr (EP == 0) {
          ((U16*)Cv)[(size_t)z * sC + (size_t)rr * N + c] = f2bf(v);
        } else if constexpr (EP == 1) {
          int mk = mask[((size_t)z * M + rr) * N + c];
          float p = mk ? __expf(v * scale) : 0.f;
          U16 pb = f2bf(p);
          ((U16*)Cv)[(size_t)z * sC + (size_t)rr * N + c] = pb;
          psum += __uint_as_float((unsigned int)pb << 16);  // sum rounded P
        } else if constexpr (EP == 2) {
          ((U16*)Cv)[(size_t)z * sC + (size_t)rr * N + c] = f2bf(v * linv);
        } else {
          ((float*)Cv)[(size_t)z * sC + (size_t)rr * N + c] = v;
        }
      }
      if constexpr (EP == 1) {
        // reduce across the 16 lanes of this quad (same row rr)
#pragma unroll
        for (int off = 8; off > 0; off >>= 1) psum += __shfl_xor(psum, off, 64);
        if (ln == 0) atomicAdd(&rowsum[(size_t)z * M + rr], psum);
      }
    }
  }
}

// ------------------------------------------------------------ fallback path --
__device__ inline float4 load4(const float* p) { return *(const float4*)p; }
__device__ inline float4 load4(const U16* p) {
  uint2 w = *(const uint2*)p;
  float2 f0 = bfp2(w.x), f1 = bfp2(w.y);
  return make_float4(f0.x, f0.y, f1.x, f1.y);
}
__device__ inline void store4(float* p, float a, float b, float c, float d) {
  *(float4*)p = make_float4(a, b, c, d);
}
__device__ inline void store4(U16* p, float a, float b, float c, float d) {
  uint2 w;
  w.x = packbf(a, b);
  w.y = packbf(c, d);
  *(uint2*)p = w;
}
template <typename TA, typename TB, typename TC>
__global__ __launch_bounds__(256) void gemm_t(
    const TA* __restrict__ A, const TB* __restrict__ B,
    TC* __restrict__ C, int M, int N, int K) {
  __shared__ float As[16][64];
  __shared__ float Bs[16][64];
  const int t = threadIdx.x;
  const int tx = t & 15, ty = t >> 4;
  const int m0 = blockIdx.y * 64;
  const int n0 = blockIdx.x * 64;
  const int arow = t >> 2, akq = (t & 3) * 4;
  const int brow = t >> 4, bcg = (t & 15) * 4;
  float acc[4][4] = {};
  for (int k0 = 0; k0 < K; k0 += 16) {
    {
      float4 f = load4(A + (size_t)(m0 + arow) * K + k0 + akq);
      As[akq + 0][arow] = f.x; As[akq + 1][arow] = f.y;
      As[akq + 2][arow] = f.z; As[akq + 3][arow] = f.w;
    }
    {
      float4 f = load4(B + (size_t)(k0 + brow) * N + n0 + bcg);
      *(float4*)&Bs[brow][bcg] = f;
    }
    __syncthreads();
#pragma unroll
    for (int kk = 0; kk < 16; ++kk) {
      float4 a = *(const float4*)&As[kk][ty * 4];
      float4 b = *(const float4*)&Bs[kk][tx * 4];
      float av[4] = {a.x, a.y, a.z, a.w};
      float bv[4] = {b.x, b.y, b.z, b.w};
#pragma unroll
      for (int i = 0; i < 4; ++i)
#pragma unroll
        for (int j = 0; j < 4; ++j) acc[i][j] += av[i] * bv[j];
    }
    __syncthreads();
  }
#pragma unroll
  for (int i = 0; i < 4; ++i)
    store4(&C[(size_t)(m0 + ty * 4 + i) * N + n0 + tx * 4],
           acc[i][0], acc[i][1], acc[i][2], acc[i][3]);
}
__global__ __launch_bounds__(256) void flash_wave(
    const U16* __restrict__ Q, const U16* __restrict__ Kd,
    const U16* __restrict__ V, const int* __restrict__ mask,
    U16* __restrict__ O) {
  __shared__ float q_s[4][DM];
  const int t = threadIdx.x;
  const int w = t >> 6;
  const int lane = t & 63;
  const int row = blockIdx.x * 4 + w;
  const int b = row >> 11;
  const size_t bo = (size_t)b * SQ * DM;
  const size_t mrow0 = (size_t)row * SQ;
  {
    const U16* qp = Q + (size_t)row * DM + lane * 16;
    uint4 w0 = *(const uint4*)qp;
    uint4 w1 = *(const uint4*)(qp + 8);
    float* dst = &q_s[w][lane * 16];
    float2 f;
    f = bfp2(w0.x); dst[0] = f.x;  dst[1] = f.y;
    f = bfp2(w0.y); dst[2] = f.x;  dst[3] = f.y;
    f = bfp2(w0.z); dst[4] = f.x;  dst[5] = f.y;
    f = bfp2(w0.w); dst[6] = f.x;  dst[7] = f.y;
    f = bfp2(w1.x); dst[8] = f.x;  dst[9] = f.y;
    f = bfp2(w1.y); dst[10] = f.x; dst[11] = f.y;
    f = bfp2(w1.z); dst[12] = f.x; dst[13] = f.y;
    f = bfp2(w1.w); dst[14] = f.x; dst[15] = f.y;
  }
  __syncthreads();
  float m = -3.0e38f, l = 0.f;
  float o[16] = {};
  const int dbase = lane * 16;
  const float* qrow = q_s[w];
  for (int j0 = 0; j0 < SQ; j0 += 64) {
    float s;
    {
      const U16* kp = Kd + bo + (size_t)(j0 + lane) * DM;
      float acc = 0.f;
      for (int d = 0; d < DM; d += 8) {
        uint4 kw = *(const uint4*)(kp + d);
        float2 a0 = bfp2(kw.x), a1 = bfp2(kw.y), a2 = bfp2(kw.z), a3 = bfp2(kw.w);
        acc += qrow[d] * a0.x + qrow[d + 1] * a0.y + qrow[d + 2] * a1.x +
               qrow[d + 3] * a1.y + qrow[d + 4] * a2.x + qrow[d + 5] * a2.y +
               qrow[d + 6] * a3.x + qrow[d + 7] * a3.y;
      }
      s = acc * 0.03125f;
      if (mask[mrow0 + j0 + lane] == 0) s = -1e10f;
    }
    float ms = s;
#pragma unroll
    for (int off = 32; off > 0; off >>= 1) ms = fmaxf(ms, __shfl_xor(ms, off, 64));
    float mn = fmaxf(m, ms);
    float alpha = __expf(m - mn);
    float p = __expf(s - mn);
    float ps = p;
#pragma unroll
    for (int off = 32; off > 0; off >>= 1) ps += __shfl_xor(ps, off, 64);
    l = l * alpha + ps;
    m = mn;
#pragma unroll
    for (int k = 0; k < 16; ++k) o[k] *= alpha;
    const U16* vp = V + bo + (size_t)j0 * DM + dbase;
    for (int j = 0; j < 64; ++j) {
      float pj = __shfl(p, j, 64);
      uint4 v0 = *(const uint4*)(vp + (size_t)j * DM);
      uint4 v1 = *(const uint4*)(vp + (size_t)j * DM + 8);
      float2 f0 = bfp2(v0.x), f1 = bfp2(v0.y), f2 = bfp2(v0.z), f3 = bfp2(v0.w);
      float2 g0 = bfp2(v1.x), g1 = bfp2(v1.y), g2 = bfp2(v1.z), g3 = bfp2(v1.w);
      o[0] += pj * f0.x;  o[1] += pj * f0.y;  o[2] += pj * f1.x;  o[3] += pj * f1.y;
      o[4] += pj * f2.x;  o[5] += pj * f2.y;  o[6] += pj * f3.x;  o[7] += pj * f3.y;
      o[8] += pj * g0.x;  o[9] += pj * g0.y;  o[10] += pj * g1.x; o[11] += pj * g1.y;
      o[12] += pj * g2.x; o[13] += pj * g2.y; o[14] += pj * g3.x; o[15] += pj * g3.y;
    }
  }
  float linv = (l > 0.f) ? (1.0f / l) : 0.f;
  U16* op = O + (size_t)row * DM + dbase;
  uint4 r0, r1;
  r0.x = packbf(o[0] * linv, o[1] * linv);
  r0.y = packbf(o[2] * linv, o[3] * linv);
  r0.z = packbf(o[4] * linv, o[5] * linv);
  r0.w = packbf(o[6] * linv, o[7] * linv);
  r1.x = packbf(o[8] * linv, o[9] * linv);
  r1.y = packbf(o[10] * linv, o[11] * linv);
  r1.z = packbf(o[12] * linv, o[13] * linv);
  r1.w = packbf(o[14] * linv, o[15] * linv);
  *(uint4*)op = r0;
  *(uint4*)(op + 8) = r1;
}

extern "C" void kernel_launch(void* const* d_in, const int* in_sizes, int n_in,
                              void* d_out, int out_size, void* d_ws, size_t ws_size,
                              hipStream_t stream) {
  const float* x  = (const float*)d_in[0];
  const int* mask = (const int*)d_in[1];
  const float* Wq = (const float*)d_in[2];
  const float* Wk = (const float*)d_in[3];
  const float* Wv = (const float*)d_in[4];
  const float* Wo = (const float*)d_in[5];
  float* out = (float*)d_out;

  const size_t MB = 1u << 20;
  const size_t E = (size_t)NB * SQ * DM;  // 8388608
  const size_t WE = (size_t)DM * DM;      // 1048576

  if (ws_size >= 121 * MB) {
    // -------- fast MFMA path --------
    char* ws = (char*)d_ws;
    U16* WT   = (U16*)ws;               // 4 x 2MiB: Wq^T,Wk^T,Wv^T,Wo^T bf16
    U16* x16  = (U16*)(ws + 8 * MB);
    U16* Q16  = (U16*)(ws + 24 * MB);   // Q,K,V contiguous at stride E elems
    U16* K16  = (U16*)(ws + 40 * MB);
    U16* V16  = (U16*)(ws + 56 * MB);
    U16* VT16 = (U16*)(ws + 72 * MB);
    U16* P16  = (U16*)(ws + 88 * MB);   // 32 MiB
    float* rs = (float*)(ws + 120 * MB);
    U16* O16  = Q16;                    // Q dead after score GEMM

    conv_f32_bf16<<<dim3(E / (256 * 8)), 256, 0, stream>>>(x, x16, rs);
    transp_w4<<<dim3(16, 16, 4), 256, 0, stream>>>(Wq, Wk, Wv, Wo, WT);

    // fused QKV: z in {0,1,2} -> Wq/Wk/Wv, writes Q16/K16/V16
    gemm_mfma<0><<<dim3(DM / 128, (NB * SQ) / 128, 3), 256, 0, stream>>>(
        x16, WT, Q16, NB * SQ, DM, DM,
        0, (long long)WE, (long long)E, nullptr, nullptr, 0.f);

    transp_bf16<<<dim3(DM / 64, SQ / 64, NB), 256, 0, stream>>>(V16, VT16, SQ, DM);

    // score: P = exp(mask(Q@K^T/32)), rowsum fused via atomics
    gemm_mfma<1><<<dim3(SQ / 128, SQ / 128, NB), 256, 0, stream>>>(
        Q16, K16, P16, SQ, SQ, DM,
        (long long)SQ * DM, (long long)SQ * DM, (long long)SQ * SQ,
        mask, rs, 0.03125f);

    // PV: O = (P @ VT^T) / rowsum
    gemm_mfma<2><<<dim3(DM / 128, SQ / 128, NB), 256, 0, stream>>>(
        P16, VT16, O16, SQ, DM, SQ,
        (long long)SQ * SQ, (long long)DM * SQ, (long long)SQ * DM,
        nullptr, rs, 0.f);

    gemm_mfma<3><<<dim3(DM / 128, (NB * SQ) / 128, 1), 256, 0, stream>>>(
        O16, WT + 3 * WE, out, NB * SQ, DM, DM,
        0, 0, 0, nullptr, nullptr, 0.f);
  } else {
    // -------- round-4 proven fallback (48 MB) --------
    U16* Kw = (U16*)d_ws;
    U16* Vw = Kw + E;
    U16* Qw = Vw + E;
    U16* Ow = Qw;
    dim3 blk(256);
    dim3 gg(DM / 64, (NB * SQ) / 64);
    gemm_t<float, float, U16><<<gg, blk, 0, stream>>>(x, Wk, Kw, NB * SQ, DM, DM);
    gemm_t<float, float, U16><<<gg, blk, 0, stream>>>(x, Wv, Vw, NB * SQ, DM, DM);
    gemm_t<float, float, U16><<<gg, blk, 0, stream>>>(x, Wq, Qw, NB * SQ, DM, DM);
    flash_wave<<<dim3((NB * SQ) / 4), blk, 0, stream>>>(Qw, Kw, Vw, mask, Ow);
    gemm_t<U16, float, float><<<gg, blk, 0, stream>>>(Ow, Wo, out, NB * SQ, DM, DM);
  }
}

// Round 8
// 353.019 us; speedup vs baseline: 1.1317x; 1.0359x over previous
//
#include <hip/hip_runtime.h>

// Single-head attention, B=4, S=2048, D=1024. fp32 in, fp32 out.
// FAST PATH (ws >= 121 MiB): all-MFMA, bf16 compute, fp32 accum.
// Algebraic fusion: out = diag(1/l) P V Wo = (P @ (x @ (Wv Wo)))/l, so the
// output projection folds into the QKV dispatch (U = x@Wvo replaces V) and
// PV writes fp32 directly to d_out. Engine: round-5 proven 128x128/BK=64/
// padded-LDS GEMM (~430 TF at this shape; m97 BK=32 measured slower, r6).
// 7 dispatches: conv(+rs zero), transpW(z4: WqT,WkT,WoT,Wv16), WvoT gemm,
// QKU(z3), transpU, score(+rowsum atomics), PVout.
// FALLBACK (small ws): round-4 proven VALU pipeline (48 MB).

#define DM 1024
#define SQ 2048
#define NB 4
typedef unsigned short U16;
typedef short bhalf8 __attribute__((ext_vector_type(8)));
typedef float f32x4 __attribute__((ext_vector_type(4)));

__device__ inline U16 f2bf(float f) {
  unsigned int u = __float_as_uint(f);
  u += 0x7FFFu + ((u >> 16) & 1u);  // RNE
  return (U16)(u >> 16);
}
__device__ inline float2 bfp2(unsigned int u) {
  float2 r;
  r.x = __uint_as_float(u << 16);
  r.y = __uint_as_float(u & 0xffff0000u);
  return r;
}
__device__ inline unsigned int packbf(float a, float b) {
  return (unsigned int)f2bf(a) | ((unsigned int)f2bf(b) << 16);
}

// ---------------------------------------------------------------- fast path --
// x fp32 -> bf16; also zeros the rowsum accumulator.
__global__ __launch_bounds__(256) void conv_f32_bf16(
    const float* __restrict__ src, U16* __restrict__ dst, float* __restrict__ rs) {
  int idx = blockIdx.x * 256 + threadIdx.x;
  if (idx < NB * SQ) rs[idx] = 0.f;
  int i = idx * 8;
  float4 a = *(const float4*)(src + i);
  float4 b = *(const float4*)(src + i + 4);
  uint4 w;
  w.x = packbf(a.x, a.y); w.y = packbf(a.z, a.w);
  w.z = packbf(b.x, b.y); w.w = packbf(b.z, b.w);
  *(uint4*)(dst + i) = w;
}

__device__ inline void ldcvt16(const float* p, U16* d) {
#pragma unroll
  for (int i = 0; i < 4; ++i) {
    float4 f = *(const float4*)(p + i * 4);
    d[i * 4 + 0] = f2bf(f.x); d[i * 4 + 1] = f2bf(f.y);
    d[i * 4 + 2] = f2bf(f.z); d[i * 4 + 3] = f2bf(f.w);
  }
}
__device__ inline void ldcvt16(const U16* p, U16* d) {
  uint4 a = *(const uint4*)p;
  uint4 b = *(const uint4*)(p + 8);
  *(uint4*)d = a;
  *(uint4*)(d + 8) = b;
}

// z=0: Wq^T -> WT; z=1: Wk^T -> WT+WE; z=2: Wo^T -> WoT; z=3: Wv straight
// conv (no transpose) -> Wv16.
__global__ __launch_bounds__(256) void transp_w4(
    const float* __restrict__ Wq, const float* __restrict__ Wk,
    const float* __restrict__ Wo, const float* __restrict__ Wv,
    U16* __restrict__ WT, U16* __restrict__ WoT, U16* __restrict__ Wv16) {
  __shared__ U16 tile[64][72];
  const int z = blockIdx.z;
  const int r0 = blockIdx.y * 64, c0 = blockIdx.x * 64;
  const int t = threadIdx.x;
  const int tr = t >> 2, tc = (t & 3) * 16;
  if (z == 3) {  // straight conv of Wv
    U16 vals[16];
    ldcvt16(Wv + (size_t)(r0 + tr) * DM + c0 + tc, vals);
    U16* op = Wv16 + (size_t)(r0 + tr) * DM + c0 + tc;
    *(uint4*)op = *(uint4*)&vals[0];
    *(uint4*)(op + 8) = *(uint4*)&vals[8];
    return;
  }
  const float* src = (z == 0) ? Wq : (z == 1) ? Wk : Wo;
  U16* d = (z == 2) ? WoT : WT + (size_t)z * DM * DM;
  ldcvt16(src + (size_t)(r0 + tr) * DM + c0 + tc, &tile[tr][tc]);
  __syncthreads();
  U16 vals[16];
#pragma unroll
  for (int m = 0; m < 16; ++m) vals[m] = tile[tc + m][tr];
  U16* op = d + (size_t)(c0 + tr) * DM + r0 + tc;
  *(uint4*)op = *(uint4*)&vals[0];
  *(uint4*)(op + 8) = *(uint4*)&vals[8];
}

// bf16 transpose [R][C] -> [C][R], grid(C/64, R/64, Z)
__global__ __launch_bounds__(256) void transp_bf16(
    const U16* __restrict__ src, U16* __restrict__ dst, int R, int C) {
  __shared__ U16 tile[64][72];
  const int z = blockIdx.z;
  src += (size_t)z * R * C;
  dst += (size_t)z * R * C;
  const int r0 = blockIdx.y * 64, c0 = blockIdx.x * 64;
  const int t = threadIdx.x;
  const int tr = t >> 2, tc = (t & 3) * 16;
  ldcvt16(src + (size_t)(r0 + tr) * C + c0 + tc, &tile[tr][tc]);
  __syncthreads();
  U16 vals[16];
#pragma unroll
  for (int m = 0; m < 16; ++m) vals[m] = tile[tc + m][tr];
  U16* op = dst + (size_t)(c0 + tr) * R + r0 + tc;
  *(uint4*)op = *(uint4*)&vals[0];
  *(uint4*)(op + 8) = *(uint4*)&vals[8];
}

// C = A @ B'^T : A[M][K] bf16, B'[N][K] bf16, fp32 accum. 128x128 tile, 4 waves,
// BK=64, padded LDS stride 72, VGPR staging. EP: 0 = bf16 store,
// 1 = exp(mask(acc*scale)) bf16 + fused rowsum atomics, 2 = fp32 store of
// acc/rowsum. Verified layouts: A/B frag [lane&15][k=(lane>>4)*8+j],
// C/D row=(lane>>4)*4+reg, col=lane&15.
template <int EP>
__global__ __launch_bounds__(256) void gemm_mfma(
    const U16* __restrict__ A, const U16* __restrict__ B, void* __restrict__ Cv,
    int M, int N, int K, long long sA, long long sB, long long sC,
    const int* __restrict__ mask, float* __restrict__ rowsum, float scale) {
  __shared__ U16 As[128 * 72];  // [m][k], stride 72 elems = 144 B
  __shared__ U16 Bs[128 * 72];  // [n][k]
  const int t = threadIdx.x;
  const int lane = t & 63, wave = t >> 6;
  const int wm = wave >> 1, wn = wave & 1;
  const int q = lane >> 4, ln = lane & 15;
  const int z = blockIdx.z;
  const int m0 = blockIdx.y * 128, n0 = blockIdx.x * 128;
  A += (size_t)z * sA;
  B += (size_t)z * sB;

  f32x4 acc[4][4] = {};

  const int srow = t >> 3;        // 0..31
  const int scol = (t & 7) * 8;   // 0..56 step 8

  for (int k0 = 0; k0 < K; k0 += 64) {
    const U16* ga = A + (size_t)(m0 + srow) * K + k0 + scol;
    const U16* gb = B + (size_t)(n0 + srow) * K + k0 + scol;
#pragma unroll
    for (int it = 0; it < 4; ++it) {
      uint4 va = *(const uint4*)(ga + (size_t)it * 32 * K);
      uint4 vb = *(const uint4*)(gb + (size_t)it * 32 * K);
      *(uint4*)&As[(it * 32 + srow) * 72 + scol] = va;
      *(uint4*)&Bs[(it * 32 + srow) * 72 + scol] = vb;
    }
    __syncthreads();
#pragma unroll
    for (int kk = 0; kk < 64; kk += 32) {
      bhalf8 af[4], bg[4];
#pragma unroll
      for (int i = 0; i < 4; ++i) {
        af[i] = *(const bhalf8*)&As[(wm * 64 + i * 16 + ln) * 72 + kk + q * 8];
        bg[i] = *(const bhalf8*)&Bs[(wn * 64 + i * 16 + ln) * 72 + kk + q * 8];
      }
#pragma unroll
      for (int i = 0; i < 4; ++i)
#pragma unroll
        for (int j = 0; j < 4; ++j)
          acc[i][j] = __builtin_amdgcn_mfma_f32_16x16x32_bf16(af[i], bg[j], acc[i][j], 0, 0, 0);
    }
    __syncthreads();
  }

  // epilogue
#pragma unroll
  for (int i = 0; i < 4; ++i) {
#pragma unroll
    for (int r = 0; r < 4; ++r) {
      const int rr = m0 + wm * 64 + i * 16 + q * 4 + r;
      float linv = 0.f;
      if constexpr (EP == 2) linv = 1.0f / (rowsum[(size_t)z * M + rr] + 1e-30f);
      float psum = 0.f;
#pragma unroll
      for (int j = 0; j < 4; ++j) {
        const int c = n0 + wn * 64 + j * 16 + ln;
        float v = acc[i][j][r];
        if constexpr (EP == 0) {
          ((U16*)Cv)[(size_t)z * sC + (size_t)rr * N + c] = f2bf(v);
        } else if constexpr (EP == 1) {
          int mk = mask[((size_t)z * M + rr) * N + c];
          float p = mk ? __expf(v * scale) : 0.f;
          U16 pb = f2bf(p);
          ((U16*)Cv)[(size_t)z * sC + (size_t)rr * N + c] = pb;
          psum += __uint_as_float((unsigned int)pb << 16);  // sum rounded P
        } else {
          ((float*)Cv)[(size_t)z * sC + (size_t)rr * N + c] = v * linv;
        }
      }
      if constexpr (EP == 1) {
        // reduce across the 16 lanes of this quad (same row rr)
#pragma unroll
        for (int off = 8; off > 0; off >>= 1) psum += __shfl_xor(psum, off, 64);
        if (ln == 0) atomicAdd(&rowsum[(size_t)z * M + rr], psum);
      }
    }
  }
}

// ------------------------------------------------------------ fallback path --
__device__ inline float4 load4(const float* p) { return *(const float4*)p; }
__device__ inline float4 load4(const U16* p) {
  uint2 w = *(const uint2*)p;
  float2 f0 = bfp2(w.x), f1 = bfp2(w.y);
  return make_float4(f0.x, f0.y, f1.x, f1.y);
}
__device__ inline void store4(float* p, float a, float b, float c, float d) {
  *(float4*)p = make_float4(a, b, c, d);
}
__device__ inline void store4(U16* p, float a, float b, float c, float d) {
  uint2 w;
  w.x = packbf(a, b);
  w.y = packbf(c, d);
  *(uint2*)p = w;
}
template <typename TA, typename TB, typename TC>
__global__ __launch_bounds__(256) void gemm_t(
    const TA* __restrict__ A, const TB* __restrict__ B,
    TC* __restrict__ C, int M, int N, int K) {
  __shared__ float As[16][64];
  __shared__ float Bs[16][64];
  const int t = threadIdx.x;
  const int tx = t & 15, ty = t >> 4;
  const int m0 = blockIdx.y * 64;
  const int n0 = blockIdx.x * 64;
  const int arow = t >> 2, akq = (t & 3) * 4;
  const int brow = t >> 4, bcg = (t & 15) * 4;
  float acc[4][4] = {};
  for (int k0 = 0; k0 < K; k0 += 16) {
    {
      float4 f = load4(A + (size_t)(m0 + arow) * K + k0 + akq);
      As[akq + 0][arow] = f.x; As[akq + 1][arow] = f.y;
      As[akq + 2][arow] = f.z; As[akq + 3][arow] = f.w;
    }
    {
      float4 f = load4(B + (size_t)(k0 + brow) * N + n0 + bcg);
      *(float4*)&Bs[brow][bcg] = f;
    }
    __syncthreads();
#pragma unroll
    for (int kk = 0; kk < 16; ++kk) {
      float4 a = *(const float4*)&As[kk][ty * 4];
      float4 b = *(const float4*)&Bs[kk][tx * 4];
      float av[4] = {a.x, a.y, a.z, a.w};
      float bv[4] = {b.x, b.y, b.z, b.w};
#pragma unroll
      for (int i = 0; i < 4; ++i)
#pragma unroll
        for (int j = 0; j < 4; ++j) acc[i][j] += av[i] * bv[j];
    }
    __syncthreads();
  }
#pragma unroll
  for (int i = 0; i < 4; ++i)
    store4(&C[(size_t)(m0 + ty * 4 + i) * N + n0 + tx * 4],
           acc[i][0], acc[i][1], acc[i][2], acc[i][3]);
}
__global__ __launch_bounds__(256) void flash_wave(
    const U16* __restrict__ Q, const U16* __restrict__ Kd,
    const U16* __restrict__ V, const int* __restrict__ mask,
    U16* __restrict__ O) {
  __shared__ float q_s[4][DM];
  const int t = threadIdx.x;
  const int w = t >> 6;
  const int lane = t & 63;
  const int row = blockIdx.x * 4 + w;
  const int b = row >> 11;
  const size_t bo = (size_t)b * SQ * DM;
  const size_t mrow0 = (size_t)row * SQ;
  {
    const U16* qp = Q + (size_t)row * DM + lane * 16;
    uint4 w0 = *(const uint4*)qp;
    uint4 w1 = *(const uint4*)(qp + 8);
    float* dst = &q_s[w][lane * 16];
    float2 f;
    f = bfp2(w0.x); dst[0] = f.x;  dst[1] = f.y;
    f = bfp2(w0.y); dst[2] = f.x;  dst[3] = f.y;
    f = bfp2(w0.z); dst[4] = f.x;  dst[5] = f.y;
    f = bfp2(w0.w); dst[6] = f.x;  dst[7] = f.y;
    f = bfp2(w1.x); dst[8] = f.x;  dst[9] = f.y;
    f = bfp2(w1.y); dst[10] = f.x; dst[11] = f.y;
    f = bfp2(w1.z); dst[12] = f.x; dst[13] = f.y;
    f = bfp2(w1.w); dst[14] = f.x; dst[15] = f.y;
  }
  __syncthreads();
  float m = -3.0e38f, l = 0.f;
  float o[16] = {};
  const int dbase = lane * 16;
  const float* qrow = q_s[w];
  for (int j0 = 0; j0 < SQ; j0 += 64) {
    float s;
    {
      const U16* kp = Kd + bo + (size_t)(j0 + lane) * DM;
      float acc = 0.f;
      for (int d = 0; d < DM; d += 8) {
        uint4 kw = *(const uint4*)(kp + d);
        float2 a0 = bfp2(kw.x), a1 = bfp2(kw.y), a2 = bfp2(kw.z), a3 = bfp2(kw.w);
        acc += qrow[d] * a0.x + qrow[d + 1] * a0.y + qrow[d + 2] * a1.x +
               qrow[d + 3] * a1.y + qrow[d + 4] * a2.x + qrow[d + 5] * a2.y +
               qrow[d + 6] * a3.x + qrow[d + 7] * a3.y;
      }
      s = acc * 0.03125f;
      if (mask[mrow0 + j0 + lane] == 0) s = -1e10f;
    }
    float ms = s;
#pragma unroll
    for (int off = 32; off > 0; off >>= 1) ms = fmaxf(ms, __shfl_xor(ms, off, 64));
    float mn = fmaxf(m, ms);
    float alpha = __expf(m - mn);
    float p = __expf(s - mn);
    float ps = p;
#pragma unroll
    for (int off = 32; off > 0; off >>= 1) ps += __shfl_xor(ps, off, 64);
    l = l * alpha + ps;
    m = mn;
#pragma unroll
    for (int k = 0; k < 16; ++k) o[k] *= alpha;
    const U16* vp = V + bo + (size_t)j0 * DM + dbase;
    for (int j = 0; j < 64; ++j) {
      float pj = __shfl(p, j, 64);
      uint4 v0 = *(const uint4*)(vp + (size_t)j * DM);
      uint4 v1 = *(const uint4*)(vp + (size_t)j * DM + 8);
      float2 f0 = bfp2(v0.x), f1 = bfp2(v0.y), f2 = bfp2(v0.z), f3 = bfp2(v0.w);
      float2 g0 = bfp2(v1.x), g1 = bfp2(v1.y), g2 = bfp2(v1.z), g3 = bfp2(v1.w);
      o[0] += pj * f0.x;  o[1] += pj * f0.y;  o[2] += pj * f1.x;  o[3] += pj * f1.y;
      o[4] += pj * f2.x;  o[5] += pj * f2.y;  o[6] += pj * f3.x;  o[7] += pj * f3.y;
      o[8] += pj * g0.x;  o[9] += pj * g0.y;  o[10] += pj * g1.x; o[11] += pj * g1.y;
      o[12] += pj * g2.x; o[13] += pj * g2.y; o[14] += pj * g3.x; o[15] += pj * g3.y;
    }
  }
  float linv = (l > 0.f) ? (1.0f / l) : 0.f;
  U16* op = O + (size_t)row * DM + dbase;
  uint4 r0, r1;
  r0.x = packbf(o[0] * linv, o[1] * linv);
  r0.y = packbf(o[2] * linv, o[3] * linv);
  r0.z = packbf(o[4] * linv, o[5] * linv);
  r0.w = packbf(o[6] * linv, o[7] * linv);
  r1.x = packbf(o[8] * linv, o[9] * linv);
  r1.y = packbf(o[10] * linv, o[11] * linv);
  r1.z = packbf(o[12] * linv, o[13] * linv);
  r1.w = packbf(o[14] * linv, o[15] * linv);
  *(uint4*)op = r0;
  *(uint4*)(op + 8) = r1;
}

extern "C" void kernel_launch(void* const* d_in, const int* in_sizes, int n_in,
                              void* d_out, int out_size, void* d_ws, size_t ws_size,
                              hipStream_t stream) {
  const float* x  = (const float*)d_in[0];
  const int* mask = (const int*)d_in[1];
  const float* Wq = (const float*)d_in[2];
  const float* Wk = (const float*)d_in[3];
  const float* Wv = (const float*)d_in[4];
  const float* Wo = (const float*)d_in[5];
  float* out = (float*)d_out;

  const size_t MB = 1u << 20;
  const size_t E = (size_t)NB * SQ * DM;  // 8388608
  const size_t WE = (size_t)DM * DM;      // 1048576

  if (ws_size >= 121 * MB) {
    // -------- fast MFMA path --------
    char* ws = (char*)d_ws;
    U16* WT   = (U16*)ws;               // slot0 Wq^T, slot1 Wk^T, slot2 Wvo^T
    U16* WoT  = (U16*)(ws + 6 * MB);    // Wo^T (2 MiB)
    U16* x16  = (U16*)(ws + 8 * MB);
    U16* Q16  = (U16*)(ws + 24 * MB);   // Q,K,U contiguous at stride E elems
    U16* K16  = (U16*)(ws + 40 * MB);
    U16* U16b = (U16*)(ws + 56 * MB);   // U = x @ (Wv Wo) = V Wo
    U16* Wv16 = (U16*)(ws + 72 * MB);   // Wv bf16 (2 MiB, dead after WvoT gemm)
    U16* UT16 = (U16*)(ws + 72 * MB);   // U^T per batch (16 MiB, written later)
    U16* P16  = (U16*)(ws + 88 * MB);   // 32 MiB
    float* rs = (float*)(ws + 120 * MB);

    conv_f32_bf16<<<dim3(E / (256 * 8)), 256, 0, stream>>>(x, x16, rs);
    transp_w4<<<dim3(16, 16, 4), 256, 0, stream>>>(Wq, Wk, Wo, Wv, WT, WoT, Wv16);

    // Wvo^T[e][d] = sum_f WoT[e][f] * Wv[d][f]  (2.1 GF, 64 blocks)
    gemm_mfma<0><<<dim3(DM / 128, DM / 128, 1), 256, 0, stream>>>(
        WoT, Wv16, WT + 2 * WE, DM, DM, DM, 0, 0, 0, nullptr, nullptr, 0.f);

    // fused Q/K/U: z in {0,1,2} -> WqT/WkT/WvoT, writes Q16/K16/U16b
    gemm_mfma<0><<<dim3(DM / 128, (NB * SQ) / 128, 3), 256, 0, stream>>>(
        x16, WT, Q16, NB * SQ, DM, DM,
        0, (long long)WE, (long long)E, nullptr, nullptr, 0.f);

    transp_bf16<<<dim3(DM / 64, SQ / 64, NB), 256, 0, stream>>>(U16b, UT16, SQ, DM);

    // score: P = exp(mask(Q@K^T/32)), rowsum fused via atomics
    gemm_mfma<1><<<dim3(SQ / 128, SQ / 128, NB), 256, 0, stream>>>(
        Q16, K16, P16, SQ, SQ, DM,
        (long long)SQ * DM, (long long)SQ * DM, (long long)SQ * SQ,
        mask, rs, 0.03125f);

    // out = (P @ UT^T) / rowsum, fp32 store direct to d_out
    gemm_mfma<2><<<dim3(DM / 128, SQ / 128, NB), 256, 0, stream>>>(
        P16, UT16, out, SQ, DM, SQ,
        (long long)SQ * SQ, (long long)DM * SQ, (long long)SQ * DM,
        nullptr, rs, 0.f);
  } else {
    // -------- round-4 proven fallback (48 MB) --------
    U16* Kw = (U16*)d_ws;
    U16* Vw = Kw + E;
    U16* Qw = Vw + E;
    U16* Ow = Qw;
    dim3 blk(256);
    dim3 gg(DM / 64, (NB * SQ) / 64);
    gemm_t<float, float, U16><<<gg, blk, 0, stream>>>(x, Wk, Kw, NB * SQ, DM, DM);
    gemm_t<float, float, U16><<<gg, blk, 0, stream>>>(x, Wv, Vw, NB * SQ, DM, DM);
    gemm_t<float, float, U16><<<gg, blk, 0, stream>>>(x, Wq, Qw, NB * SQ, DM, DM);
    flash_wave<<<dim3((NB * SQ) / 4), blk, 0, stream>>>(Qw, Kw, Vw, mask, Ow);
    gemm_t<U16, float, float><<<gg, blk, 0, stream>>>(Ow, Wo, out, NB * SQ, DM, DM);
  }
}